// Round 11
// baseline (217.839 us; speedup 1.0000x reference)
//
#include <hip/hip_runtime.h>
#include <cstddef>
#include <cstdint>

#define SCALE_WEIGHT 0.70710678118654752440f

static constexpr int B_ = 8, C_ = 512, T_ = 2048, S_ = 2048;
static constexpr size_t BCT_ = (size_t)B_ * C_ * T_;   // 8.4M  (ctx region elems)
static constexpr size_t BTS_ = (size_t)B_ * T_ * S_;   // 33.5M (attn region elems)

typedef _Float16 half_t;
typedef half_t half8  __attribute__((ext_vector_type(8)));
typedef half_t half4v __attribute__((ext_vector_type(4)));
typedef float  floatx4 __attribute__((ext_vector_type(4)));

// async global->LDS, 16B per lane. LDS dest = wave-uniform base + lane*16.
__device__ __forceinline__ void gload_lds16(const void* g, void* l) {
    __builtin_amdgcn_global_load_lds(
        (const __attribute__((address_space(1))) void*)g,
        (__attribute__((address_space(3))) void*)l, 16, 0, 0);
}

// ---------------------------------------------------------------------------
// merged pre-pass: z<16 -> 64x64 transpose+convert of x/top; z==16 -> flat
// f32->f16 convert of comb and W (grid-stride over the plane's 256 blocks).
// ---------------------------------------------------------------------------
__global__ __launch_bounds__(256) void pre_kernel(
    const float* __restrict__ x, const float* __restrict__ top,
    const float* __restrict__ comb, const float* __restrict__ W,
    half_t* __restrict__ xT, half_t* __restrict__ topT,
    half_t* __restrict__ combh, half_t* __restrict__ Wh)
{
    const int z = blockIdx.z;
    if (z < 16) {
        __shared__ float tile[64][65];
        const float* in = (z < 8) ? x : top;
        half_t* outp = (z < 8) ? xT : topT;
        const int b  = z & 7;
        const int r0 = blockIdx.y * 64, c0 = blockIdx.x * 64;
        const float* ib = in + (size_t)b * C_ * T_;
        half_t* ob = outp + (size_t)b * C_ * T_;
        const int t  = threadIdx.x;
        const int rr = t >> 4, cq = t & 15;
        #pragma unroll
        for (int i = 0; i < 4; ++i) {
            const int r = rr + i * 16;
            float4 v = *(const float4*)&ib[(size_t)(r0 + r) * T_ + c0 + cq * 4];
            tile[cq * 4 + 0][r] = v.x;
            tile[cq * 4 + 1][r] = v.y;
            tile[cq * 4 + 2][r] = v.z;
            tile[cq * 4 + 3][r] = v.w;
        }
        __syncthreads();
        const int cw = t >> 4, rq = (t & 15) * 4;
        #pragma unroll
        for (int i = 0; i < 4; ++i) {
            const int c = cw + i * 16;
            half4v h = {(half_t)tile[c][rq + 0], (half_t)tile[c][rq + 1],
                        (half_t)tile[c][rq + 2], (half_t)tile[c][rq + 3]};
            *(half4v*)&ob[(size_t)(c0 + c) * C_ + r0 + rq] = h;
        }
    } else {
        const int n4a = (int)((size_t)B_ * C_ * S_ / 4);
        const int n4tot = n4a + C_ * C_ / 4;
        const int planeT = 32 * 8 * 256;
        for (int i = (blockIdx.y * 32 + blockIdx.x) * 256 + threadIdx.x;
             i < n4tot; i += planeT) {
            const float4* src; half4v* dst; int j;
            if (i < n4a) { src = (const float4*)comb; dst = (half4v*)combh; j = i; }
            else         { src = (const float4*)W;    dst = (half4v*)Wh;    j = i - n4a; }
            float4 v = src[j];
            dst[j] = (half4v){(half_t)v.x, (half_t)v.y, (half_t)v.z, (half_t)v.w};
        }
    }
}

// ---------------------------------------------------------------------------
// Depth-3 ring MFMA fp16 GEMM: 128x128 tile, 4 waves (64x64 each), BK=32,
// 4-slot LDS ring (4x16KB = 64KB -> 2 blocks/CU), prefetch distance 3 K-tiles,
// counted vmcnt(12), R3's 2-barrier step semantics per slot.
// Race-safety: STAGE(t+3) writes slot (t+3)&3 == (t-1)&3, whose compute ended
// before step t-1's closing barrier, and the stage is issued after it.
// LDS row = 32 halves = 64B = 4 slots of 16B; slot = kg ^ (row&3) swizzle,
// inverse on the per-lane global source (both-sides involution, 2-way = free).
// A: [M][K] f16 k-contig.  B: [N][K] f16 k-contig.  C: [M][N].
// EPI 0: f32 store.  EPI 1 (K1): f16 store of (acc + bias[n] + base[b][n][m])*SCALE.
// ---------------------------------------------------------------------------
template<int EPI>
__global__ __launch_bounds__(256) void gemm_d3_kernel(
    const half_t* __restrict__ A, const half_t* __restrict__ Bm,
    float* __restrict__ Cout, half_t* __restrict__ CoutH,
    const float* __restrict__ base, const float* __restrict__ bias,
    int M, int N, int K, size_t sA, size_t sB, size_t sC)
{
    __shared__ __align__(128) char smem[65536];
    // A slot s @ s*8192 ; B slot s @ 32768 + s*8192

    const int tid  = threadIdx.x;
    const int lane = tid & 63, w = tid >> 6;
    const int wr = w >> 1, wc = w & 1;
    const int b  = blockIdx.z;
    const int m0 = blockIdx.y * 128, n0 = blockIdx.x * 128;

    const half_t* Ab = A  + (size_t)b * sA;
    const half_t* Bb = Bm + (size_t)b * sB;

    // staging: wave w owns rows [w*32, w*32+32), 2 chunks of 16 rows per op.
    const int lr  = lane >> 2;                 // row within 16-row chunk
    const int ks8 = ((lane & 3) ^ (lr & 3)) << 3;  // swizzled src k-slot (f16 units)
    const half_t* aG0 = Ab + (size_t)(m0 + w * 32 +      lr) * K + ks8;
    const half_t* aG1 = Ab + (size_t)(m0 + w * 32 + 16 + lr) * K + ks8;
    const half_t* bG0 = Bb + (size_t)(n0 + w * 32 +      lr) * K + ks8;
    const half_t* bG1 = Bb + (size_t)(n0 + w * 32 + 16 + lr) * K + ks8;
    const int dO0 = (w * 32) * 64, dO1 = (w * 32 + 16) * 64;

    // fragment ds_read byte offsets within a slot
    const int fr = lane & 15, kg = lane >> 4, q4 = kg * 4;
    int aoff[4], boff[4];
    #pragma unroll
    for (int mi = 0; mi < 4; ++mi) {
        const int m = wr * 64 + mi * 16 + fr;
        aoff[mi] = m * 64 + ((kg ^ (m & 3)) << 4);
    }
    #pragma unroll
    for (int nj = 0; nj < 4; ++nj) {
        const int n = wc * 64 + nj * 16 + fr;
        boff[nj] = 32768 + n * 64 + ((kg ^ (n & 3)) << 4);
    }

    floatx4 acc[4][4];
    #pragma unroll
    for (int mi = 0; mi < 4; ++mi)
        #pragma unroll
        for (int nj = 0; nj < 4; ++nj)
            acc[mi][nj] = (floatx4){0.f, 0.f, 0.f, 0.f};

    auto STAGE = [&](int t) {
        const int k0 = t * 32;
        char* s = smem + (t & 3) * 8192;
        gload_lds16(aG0 + k0, s + dO0);
        gload_lds16(aG1 + k0, s + dO1);
        gload_lds16(bG0 + k0, s + 32768 + dO0);
        gload_lds16(bG1 + k0, s + 32768 + dO1);
    };

    auto COMPUTE = [&](int t) {
        const char* s = smem + (t & 3) * 8192;
        half8 af[4], bf[4];
        #pragma unroll
        for (int mi = 0; mi < 4; ++mi) af[mi] = *(const half8*)(s + aoff[mi]);
        #pragma unroll
        for (int nj = 0; nj < 4; ++nj) bf[nj] = *(const half8*)(s + boff[nj]);
        #pragma unroll
        for (int mi = 0; mi < 4; ++mi)
            #pragma unroll
            for (int nj = 0; nj < 4; ++nj)
                acc[mi][nj] = __builtin_amdgcn_mfma_f32_16x16x32_f16(
                    af[mi], bf[nj], acc[mi][nj], 0, 0, 0);
    };

    const int NT = K >> 5;                     // K/32 tiles (>=16 here)
    STAGE(0); STAGE(1); STAGE(2);
    #pragma unroll 1
    for (int t = 0; t < NT - 3; ++t) {
        STAGE(t + 3);                          // slot freed at end of step t-1
        asm volatile("s_waitcnt vmcnt(12)" ::: "memory");  // kt t's loads landed
        __builtin_amdgcn_s_barrier();
        __builtin_amdgcn_sched_barrier(0);
        COMPUTE(t);
        asm volatile("s_waitcnt lgkmcnt(0)" ::: "memory"); // ds_reads complete
        __builtin_amdgcn_sched_barrier(0);
        __builtin_amdgcn_s_barrier();          // slot free to overwrite
        __builtin_amdgcn_sched_barrier(0);
    }
    // tail: drain 8 -> 4 -> 0 (no more stages, no closing barriers needed)
    asm volatile("s_waitcnt vmcnt(8)" ::: "memory");
    __builtin_amdgcn_s_barrier();
    __builtin_amdgcn_sched_barrier(0);
    COMPUTE(NT - 3);
    asm volatile("s_waitcnt vmcnt(4)" ::: "memory");
    __builtin_amdgcn_s_barrier();
    __builtin_amdgcn_sched_barrier(0);
    COMPUTE(NT - 2);
    asm volatile("s_waitcnt vmcnt(0)" ::: "memory");
    __builtin_amdgcn_s_barrier();
    __builtin_amdgcn_sched_barrier(0);
    COMPUTE(NT - 1);

    if constexpr (EPI == 0) {
        float* Cb = Cout + (size_t)b * sC;
        #pragma unroll
        for (int mi = 0; mi < 4; ++mi) {
            const int row = m0 + wr * 64 + mi * 16 + q4;
            #pragma unroll
            for (int nj = 0; nj < 4; ++nj) {
                const int col = n0 + wc * 64 + nj * 16 + fr;
                #pragma unroll
                for (int r = 0; r < 4; ++r)
                    Cb[(size_t)(row + r) * N + col] = acc[mi][nj][r];
            }
        }
    } else {
        half_t* Cb = CoutH + (size_t)b * sC;
        #pragma unroll
        for (int nj = 0; nj < 4; ++nj) {
            const int col = n0 + wc * 64 + nj * 16 + fr;
            const float bn = bias[col];
            const float* bp = base + ((size_t)b * N + col) * (size_t)M;
            #pragma unroll
            for (int mi = 0; mi < 4; ++mi) {
                const int row = m0 + wr * 64 + mi * 16 + q4;
                #pragma unroll
                for (int r = 0; r < 4; ++r) {
                    float v = (acc[mi][nj][r] + bn + bp[row + r]) * SCALE_WEIGHT;
                    Cb[(size_t)(row + r) * N + col] = (half_t)v;
                }
            }
        }
    }
}

// ---------------------------------------------------------------------------
// row softmax over S, in-place f32 + fp16 copy for the K4 MFMA operand
// ---------------------------------------------------------------------------
__global__ __launch_bounds__(256) void k3_softmax_kernel(
    float* __restrict__ logits, half_t* __restrict__ attnh)
{
    float* p = logits + (size_t)blockIdx.x * S_;
    half4v* ph = (half4v*)(attnh + (size_t)blockIdx.x * S_);
    const int tid = threadIdx.x;
    float4 v0 = *(const float4*)&p[tid * 4];
    float4 v1 = *(const float4*)&p[tid * 4 + 1024];

    float mx = fmaxf(fmaxf(fmaxf(v0.x, v0.y), fmaxf(v0.z, v0.w)),
                     fmaxf(fmaxf(v1.x, v1.y), fmaxf(v1.z, v1.w)));
    #pragma unroll
    for (int off = 32; off; off >>= 1)
        mx = fmaxf(mx, __shfl_xor(mx, off));

    __shared__ float sm[4];
    __shared__ float ss[4];
    const int wid = tid >> 6, lane = tid & 63;
    if (lane == 0) sm[wid] = mx;
    __syncthreads();
    const float rmax = fmaxf(fmaxf(sm[0], sm[1]), fmaxf(sm[2], sm[3]));

    float e[8];
    e[0] = __expf(v0.x - rmax); e[1] = __expf(v0.y - rmax);
    e[2] = __expf(v0.z - rmax); e[3] = __expf(v0.w - rmax);
    e[4] = __expf(v1.x - rmax); e[5] = __expf(v1.y - rmax);
    e[6] = __expf(v1.z - rmax); e[7] = __expf(v1.w - rmax);

    float sum = 0.f;
    #pragma unroll
    for (int i = 0; i < 8; ++i) sum += e[i];
    #pragma unroll
    for (int off = 32; off; off >>= 1)
        sum += __shfl_xor(sum, off);
    if (lane == 0) ss[wid] = sum;
    __syncthreads();
    const float inv = 1.f / (ss[0] + ss[1] + ss[2] + ss[3]);

    float4 r0, r1;
    r0.x = e[0] * inv; r0.y = e[1] * inv; r0.z = e[2] * inv; r0.w = e[3] * inv;
    r1.x = e[4] * inv; r1.y = e[5] * inv; r1.z = e[6] * inv; r1.w = e[7] * inv;
    *(float4*)&p[tid * 4] = r0;
    *(float4*)&p[tid * 4 + 1024] = r1;
    ph[tid]       = (half4v){(half_t)r0.x, (half_t)r0.y, (half_t)r0.z, (half_t)r0.w};
    ph[tid + 256] = (half4v){(half_t)r1.x, (half_t)r1.y, (half_t)r1.z, (half_t)r1.w};
}

extern "C" void kernel_launch(void* const* d_in, const int* in_sizes, int n_in,
                              void* d_out, int out_size, void* d_ws, size_t ws_size,
                              hipStream_t stream) {
    const float* base = (const float*)d_in[0];  // [B,C,T,1]
    const float* x    = (const float*)d_in[1];  // [B,C,T,1]
    const float* top  = (const float*)d_in[2];  // [B,C,S]
    const float* comb = (const float*)d_in[3];  // [B,C,S]
    const float* W    = (const float*)d_in[4];  // [C,C]
    const float* bias = (const float*)d_in[5];  // [C]

    float* out    = (float*)d_out;
    float* ctx    = out;          // [B,C,T] final context output (f32)
    float* logits = out + BCT_;   // [B,T,S] logits -> attn output (f32)

    // fp16 staging in the ctx region of d_out (dead before K4 rewrites it):
    half_t* xT   = (half_t*)d_out;        // [B][T][C] f16
    half_t* topT = xT + BCT_;             // [B][S][C] f16

    // ws: attnh [B][T][S] f16 (67MB, tgtT aliases its head — dead before K3),
    //     combh [B][C][S] f16 (16.8MB), Wh [C][C] f16 (0.5MB).
    half_t* attnh = (half_t*)d_ws;
    half_t* tgtT  = attnh;                       // [B][T][C] f16, alias (see above)
    half_t* combh = attnh + BTS_;
    half_t* Wh    = combh + (size_t)B_ * C_ * S_;

    // pre-pass (1 launch): both transposes + both converts
    pre_kernel<<<dim3(32, 8, 17), 256, 0, stream>>>(
        x, top, comb, W, xT, topT, combh, Wh);

    // K1: tgtT[b][t][o] = (x^T W^T + b + base)*SCALE   M=T,N=C,K=C, sB=0 (shared W)
    gemm_d3_kernel<1><<<dim3(C_ / 128, T_ / 128, B_), 256, 0, stream>>>(
        xT, Wh, nullptr, tgtT, base, bias,
        T_, C_, C_, (size_t)T_ * C_, 0, (size_t)T_ * C_);

    // K2: logits[b][t][s] = tgtT . topT                M=T,N=S,K=C
    gemm_d3_kernel<0><<<dim3(S_ / 128, T_ / 128, B_), 256, 0, stream>>>(
        tgtT, topT, logits, nullptr, nullptr, nullptr,
        T_, S_, C_, (size_t)T_ * C_, (size_t)S_ * C_, (size_t)T_ * S_);

    // K3: softmax rows, write f32 attn (output) + f16 attn (K4 operand)
    k3_softmax_kernel<<<dim3(B_ * T_), 256, 0, stream>>>(logits, attnh);

    // K4: ctx[b][c][t] = combh . attnh                 M=C,N=T,K=S
    gemm_d3_kernel<0><<<dim3(T_ / 128, C_ / 128, B_), 256, 0, stream>>>(
        combh, attnh, ctx, nullptr, nullptr, nullptr,
        C_, T_, S_, (size_t)C_ * S_, (size_t)T_ * S_, (size_t)C_ * T_);
}